// Round 1
// baseline (686.504 us; speedup 1.0000x reference)
//
#include <hip/hip_runtime.h>
#include <cstdint>

// BinaryMLP fused forward for MI355X (gfx950).
// h1 = relu(x @ sign(W1)^T + b1); h2 = relu(h1 @ sign(W2)^T + b2);
// h3 = relu(h2 @ sign(W3)^T + b3); out = h3 @ W4^T + b4
// B=524288, D_IN=196 (pad 224), H=128, D_OUT=10 (pad 16).
//
// Strategy: HBM-bound on x (411 MB). One fused kernel, BM=64 rows/block,
// bf16 MFMA 16x16x32, h kept in LDS, weights binarized to bf16 +-1 by a prep
// kernel into d_ws. Layers 2-4 use a k-permutation (p = 2w + h within 32-col
// groups) so the MFMA C->LDS write packs two bf16 into one b32; prep applies
// the matching permutation to W2/W3/W4 columns.

typedef __attribute__((ext_vector_type(8))) short bf16x8;   // 8 bf16 (4 VGPRs)
typedef __attribute__((ext_vector_type(4))) float f32x4;    // MFMA accumulator

typedef unsigned short u16;
typedef unsigned int u32;

// ws element offsets (bf16 units)
#define WS_W1 0        // [128][224]  straight, zero-padded k>=196
#define WS_W2 28672    // [128][128]  k-permuted
#define WS_W3 45056    // [128][128]  k-permuted
#define WS_W4 61440    // [16][128]   k-permuted, rows 10..15 zero
#define WS_TOTAL 63488

__device__ __forceinline__ u32 bf16_rne(float x) {
  u32 u = __float_as_uint(x);
  return (u + 0x7FFFu + ((u >> 16) & 1u)) >> 16;
}

__device__ __forceinline__ u16 sign_bf16(float v) {
  return (v > 0.f) ? 0x3F80u : ((v < 0.f) ? 0xBF80u : 0u);
}

// inverse column permutation: physical p -> logical k
__device__ __forceinline__ int kperm_inv(int p) {
  return ((p & 31) >> 1) + ((p & 1) << 4) + ((p >> 5) << 5);
}

__global__ __launch_bounds__(256) void prep_kernel(
    const float* __restrict__ W1, const float* __restrict__ W2,
    const float* __restrict__ W3, const float* __restrict__ W4,
    u16* __restrict__ ws) {
  int idx = blockIdx.x * 256 + threadIdx.x;   // grid 248 -> 63488 threads exact
  if (idx < WS_W2) {
    int n = idx / 224, k = idx - n * 224;
    float v = (k < 196) ? W1[n * 196 + k] : 0.f;
    ws[idx] = (k < 196) ? sign_bf16(v) : 0u;
  } else if (idx < WS_W3) {
    int j = idx - WS_W2; int n = j >> 7, p = j & 127;
    ws[idx] = sign_bf16(W2[(n << 7) + kperm_inv(p)]);
  } else if (idx < WS_W4) {
    int j = idx - WS_W3; int n = j >> 7, p = j & 127;
    ws[idx] = sign_bf16(W3[(n << 7) + kperm_inv(p)]);
  } else if (idx < WS_TOTAL) {
    int j = idx - WS_W4; int c = j >> 7, p = j & 127;
    ws[idx] = (c < 10) ? (u16)bf16_rne(W4[(c << 7) + kperm_inv(p)]) : 0u;
  }
}

// One hidden layer: [64,KP] bf16 (src, row stride SSTR bytes) x Wp^T -> relu
// -> packed-perm bf16 [64][136] into dst (row stride 272 bytes).
// Wave tile: 32 rows x 64 cols (2x4 MFMA tiles), 4 waves in 2x2.
template <int KP, int SSTR>
__device__ __forceinline__ void layer_fwd(
    const char* __restrict__ src, char* __restrict__ dst,
    const u16* __restrict__ Wp, const float* __restrict__ bias,
    int m, int q, int wr, int wc) {
  f32x4 acc[2][4];
#pragma unroll
  for (int rt = 0; rt < 2; ++rt)
#pragma unroll
    for (int ct = 0; ct < 4; ++ct)
      acc[rt][ct] = (f32x4){0.f, 0.f, 0.f, 0.f};

  const u16* wb = Wp + (wc * 64 + m) * KP + q * 8;      // B-frag base (elems)
  const char* ab = src + (wr * 32 + m) * SSTR + q * 16; // A-frag base (bytes)

#pragma unroll
  for (int ks = 0; ks < KP / 32; ++ks) {
    bf16x8 b[4];
#pragma unroll
    for (int ct = 0; ct < 4; ++ct)
      b[ct] = *(const bf16x8*)(wb + ct * 16 * KP + ks * 32);
#pragma unroll
    for (int rt = 0; rt < 2; ++rt) {
      bf16x8 a = *(const bf16x8*)(ab + rt * 16 * SSTR + ks * 64);
#pragma unroll
      for (int ct = 0; ct < 4; ++ct)
        acc[rt][ct] =
            __builtin_amdgcn_mfma_f32_16x16x32_bf16(a, b[ct], acc[rt][ct], 0, 0, 0);
    }
  }

  // epilogue: bias + relu, pack col pairs (n, n+16) -> one b32 at perm position
#pragma unroll
  for (int rt = 0; rt < 2; ++rt) {
#pragma unroll
    for (int cp = 0; cp < 2; ++cp) {
      int g = wc * 2 + cp;                 // 32-col group index
      float bi0 = bias[g * 32 + m];
      float bi1 = bias[g * 32 + 16 + m];
#pragma unroll
      for (int j = 0; j < 4; ++j) {
        float v0 = fmaxf(acc[rt][2 * cp][j] + bi0, 0.f);
        float v1 = fmaxf(acc[rt][2 * cp + 1][j] + bi1, 0.f);
        int row = wr * 32 + rt * 16 + q * 4 + j;
        *(u32*)(dst + row * 272 + m * 4 + g * 64) =
            bf16_rne(v0) | (bf16_rne(v1) << 16);
      }
    }
  }
}

__global__ __launch_bounds__(256, 2) void mlp_kernel(
    const float* __restrict__ x, const u16* __restrict__ ws,
    const float* __restrict__ b1, const float* __restrict__ b2,
    const float* __restrict__ b3, const float* __restrict__ b4,
    float* __restrict__ out) {
  __shared__ char smemA[64 * 448];  // x as bf16 [64][224] ; later h2 [64][136]
  __shared__ char smemB[64 * 272];  // h1 / h3 [64][136]

  const int tid = threadIdx.x;
  const int lane = tid & 63;
  const int wave = tid >> 6;
  const int m = lane & 15;
  const int q = lane >> 4;
  const int wr = wave >> 1, wc = wave & 1;
  const size_t rowbase = (size_t)blockIdx.x * 64;

  // ---- stage x: 64x196 fp32 -> bf16 LDS [64][224] (coalesced float4) ----
  const float4* xsrc = (const float4*)(x + rowbase * 196);
#pragma unroll
  for (int it = 0; it < 13; ++it) {
    int i = it * 256 + tid;            // float4 index, 3136 total (49 per row)
    if (i < 3136) {
      float4 v = xsrc[i];
      int r = i / 49;
      int c4 = i - r * 49;
      u32 lo = bf16_rne(v.x) | (bf16_rne(v.y) << 16);
      u32 hi = bf16_rne(v.z) | (bf16_rne(v.w) << 16);
      *(uint2*)(smemA + r * 448 + c4 * 8) = make_uint2(lo, hi);
    }
  }
  // zero-pad cols [196,224)
  for (int i = tid; i < 448; i += 256) {
    int r = i / 7, c = i - r * 7;
    *(uint2*)(smemA + r * 448 + 392 + c * 8) = make_uint2(0u, 0u);
  }
  __syncthreads();

  layer_fwd<224, 448>(smemA, smemB, ws + WS_W1, b1, m, q, wr, wc);
  __syncthreads();
  layer_fwd<128, 272>(smemB, smemA, ws + WS_W2, b2, m, q, wr, wc);
  __syncthreads();
  layer_fwd<128, 272>(smemA, smemB, ws + WS_W3, b3, m, q, wr, wc);
  __syncthreads();

  // ---- layer 4: [64,128] x W4p[16][128] -> out[64][10] (fp32) ----
  {
    const int rb = wave * 16;  // each wave one 16-row block
    f32x4 acc = (f32x4){0.f, 0.f, 0.f, 0.f};
    const char* ab = smemB + (rb + m) * 272 + q * 16;
    const u16* wb = ws + WS_W4 + m * 128 + q * 8;
#pragma unroll
    for (int ks = 0; ks < 4; ++ks) {
      bf16x8 a = *(const bf16x8*)(ab + ks * 64);
      bf16x8 b = *(const bf16x8*)(wb + ks * 32);
      acc = __builtin_amdgcn_mfma_f32_16x16x32_bf16(a, b, acc, 0, 0, 0);
    }
    if (m < 10) {
      float bi = b4[m];
#pragma unroll
      for (int j = 0; j < 4; ++j) {
        size_t row = rowbase + rb + q * 4 + j;
        out[row * 10 + m] = acc[j] + bi;
      }
    }
  }
}

extern "C" void kernel_launch(void* const* d_in, const int* in_sizes, int n_in,
                              void* d_out, int out_size, void* d_ws, size_t ws_size,
                              hipStream_t stream) {
  const float* x  = (const float*)d_in[0];
  const float* W1 = (const float*)d_in[1];
  const float* b1 = (const float*)d_in[2];
  const float* W2 = (const float*)d_in[3];
  const float* b2 = (const float*)d_in[4];
  const float* W3 = (const float*)d_in[5];
  const float* b3 = (const float*)d_in[6];
  const float* W4 = (const float*)d_in[7];
  const float* b4 = (const float*)d_in[8];
  u16* ws = (u16*)d_ws;          // needs 126976 B
  float* out = (float*)d_out;

  prep_kernel<<<248, 256, 0, stream>>>(W1, W2, W3, W4, ws);
  mlp_kernel<<<8192, 256, 0, stream>>>(x, ws, b1, b2, b3, b4, out);
}